// Round 14
// baseline (223.174 us; speedup 1.0000x reference)
//
#include <hip/hip_runtime.h>

// VectorQuantizer on MI355X (gfx950). Round 13: occupancy fix — K1 wave tile
// m=2 (32 pts/wave, 64 A-VGPRs), 1024 blocks (4/CU) instead of 512 (2/CU).
// Main loop = r10-style simple body (3 scheduling nulls -> trust compiler).
// d_out (f32): [z_q 33554432][idx 131072][loss 1]  (out_size 33685505)
// Scratch inside z_q's byte region (overwritten by K3 at the end):
//   bytes [67108864, 67633152)  bf16 codebook image in MFMA-fragment order
//   bytes [68157440, 69206016)  cand4: u64[131072] packed top-4 codes
//   bytes [69206016, 69210112)  enrm: f32[1024] exact np-pairwise codebook norms
// Loss slot outf[33685504] = accumulator (K0 zeroes, K2 adds, K4 rescales).

typedef __attribute__((ext_vector_type(8))) short short8;
typedef __attribute__((ext_vector_type(4))) float f32x4;
typedef unsigned long long u64;

#define IDX_OFF   33554432u
#define LOSS_OFF  33685504u
#define IMG_BYTE  67108864u
#define CAND_BYTE 68157440u
#define ENRM_BYTE 69206016u

__device__ __forceinline__ unsigned short f2bf(float f) {
  unsigned u = __float_as_uint(f);
  unsigned r = (u + 0x7FFFu + ((u >> 16) & 1u)) >> 16;  // RNE
  return (unsigned short)r;
}

// numpy pairwise combine of 8 accumulators
#define COMB(r) __fadd_rn(__fadd_rn(__fadd_rn(r[0], r[1]), __fadd_rn(r[2], r[3])), \
                          __fadd_rn(__fadd_rn(r[4], r[5]), __fadd_rn(r[6], r[7])))

// ---------------- K0: codebook image in MFMA-fragment order + zero loss -------
// img: 16B at (s*8+ks)*1024 + lane*16 holds code s*16+(lane&15),
// d = ks*32 + (lane>>4)*8 + 0..7  (s = step index 0..63).
extern "C" __global__ __launch_bounds__(256) void vq_r13_k0(const float* __restrict__ cb,
                                                            unsigned char* __restrict__ img,
                                                            float* __restrict__ outf) {
  unsigned tid = blockIdx.x * 256u + threadIdx.x;  // 131072 = (code, dpair)
  unsigned code = tid >> 7, dp = tid & 127u;
  const float* p = cb + (size_t)code * 256u + dp * 2u;
  unsigned u = ((unsigned)f2bf(p[1]) << 16) | (unsigned)f2bf(p[0]);
  unsigned s = code >> 4, c16 = code & 15;
  unsigned ks = dp >> 4, g = (dp >> 2) & 3, j = dp & 3;
  unsigned byte = (s * 8u + ks) * 1024u + (g * 16u + c16) * 16u + j * 4u;
  *(unsigned*)(img + byte) = u;
  if (tid == 0) outf[LOSS_OFF] = 0.0f;
}

// ---------------- K0b: exact np-f32 pairwise codebook norms -------------------
extern "C" __global__ __launch_bounds__(256) void vq_r13_k0b(const float* __restrict__ cb,
                                                             float* __restrict__ enrm) {
#pragma clang fp contract(off)
  int c = blockIdx.x * 256 + threadIdx.x;  // 4 blocks -> 1024 codes
  const float* e = cb + (size_t)c * 256u;
  float h[2];
#pragma unroll
  for (int half = 0; half < 2; ++half) {
    float r[8];
#pragma unroll
    for (int j = 0; j < 8; ++j) {
      float v = e[half * 128 + j];
      r[j] = __fmul_rn(v, v);
    }
    for (int i = 8; i < 128; i += 8) {
#pragma unroll
      for (int j = 0; j < 8; ++j) {
        float v = e[half * 128 + i + j];
        r[j] = __fadd_rn(r[j], __fmul_rn(v, v));
      }
    }
    h[half] = COMB(r);
  }
  enrm[c] = __fadd_rn(h[0], h[1]);
}

// ---------------- K1: m=2 A-in-regs MFMA GEMM, B direct global->reg -----------
// 256 thr (4 waves), block = 128 pts x 1024 codes, 1024 blocks (4/CU).
// Wave owns 32 pts: a[2][8] = 64 VGPRs. B frags direct from L2-hot image.
extern "C" __global__ __launch_bounds__(256, 3) void vq_r13_k1(const float* __restrict__ x,
                                                               const unsigned char* __restrict__ img,
                                                               u64* __restrict__ cand4) {
  __shared__ __attribute__((aligned(16))) char lds[32768];
  const int t = threadIdx.x;
  const int bid = blockIdx.x;  // 1024 blocks, 128 pts each
  const int lane = t & 63;
  const int w = t >> 6;
  const int g = lane >> 4, c16 = lane & 15;

  const size_t xbase = (size_t)(bid >> 5) * 1048576u + (size_t)(bid & 31) * 128u;

  // ---- A: 2 halves of 64 pts staged via 32KB LDS transpose, frags to regs ----
  short8 a[2][8];
  for (int h = 0; h < 2; ++h) {
#pragma unroll 4
    for (int it = 0; it < 8; ++it) {
      int flat = it * 256 + t;   // [0, 2048): 16 pt-groups x 128 dpairs
      int pt4 = flat & 15;
      int dp = flat >> 4;
      const float* px = x + xbase + (size_t)(2 * dp) * 4096u + (unsigned)(h * 64 + pt4 * 4);
      float4 fa = *(const float4*)px;           // d = 2*dp,   4 pts
      float4 fb = *(const float4*)(px + 4096);  // d = 2*dp+1, 4 pts
      const float* fap = (const float*)&fa;
      const float* fbp = (const float*)&fb;
#pragma unroll
      for (int k = 0; k < 4; ++k) {
        unsigned u = ((unsigned)f2bf(fbp[k]) << 16) | (unsigned)f2bf(fap[k]);
        int r = pt4 * 4 + k;  // local row 0..63
        *(unsigned*)(lds + r * 512 + ((dp * 4) ^ ((r & 31) << 2))) = u;
      }
    }
    __syncthreads();
    if ((w >> 1) == h) {
#pragma unroll
      for (int m = 0; m < 2; ++m) {
        const int r = (w & 1) * 32 + m * 16 + c16;  // local row
        const int rsw = (r & 31) << 2;
#pragma unroll
        for (int ks = 0; ks < 8; ++ks) {
          union { unsigned q4[4]; short8 s8; } uu;
#pragma unroll
          for (int jj = 0; jj < 4; ++jj)
            uu.q4[jj] = *(const unsigned*)(lds + r * 512 + (((ks * 16 + g * 4 + jj) * 4) ^ rsw));
          a[m][ks] = uu.s8;
        }
      }
    }
    __syncthreads();
  }

  // ---- main loop: 64 steps, B frags direct from global (L2-hot) ----
  float t1[8], t2[8];
#pragma unroll
  for (int s = 0; s < 8; ++s) { t1[s] = -__builtin_inff(); t2[s] = -__builtin_inff(); }

  const unsigned char* gW = img + (unsigned)(lane * 16);
  for (int s = 0; s < 64; ++s) {
    const unsigned char* gs = gW + (unsigned)(s * 8192);
    short8 bf[8];
#pragma unroll
    for (int ks = 0; ks < 8; ++ks)
      bf[ks] = *(const short8*)(gs + ks * 1024);  // contiguous 1KB/wave
    f32x4 acc0 = (f32x4){0.f, 0.f, 0.f, 0.f};
    f32x4 acc1 = (f32x4){0.f, 0.f, 0.f, 0.f};
#pragma unroll
    for (int ks = 0; ks < 8; ++ks) {
      acc0 = __builtin_amdgcn_mfma_f32_16x16x32_bf16(a[0][ks], bf[ks], acc0, 0, 0, 0);
      acc1 = __builtin_amdgcn_mfma_f32_16x16x32_bf16(a[1][ks], bf[ks], acc1, 0, 0, 0);
    }
    const unsigned code = (unsigned)(s * 16 + c16);
#define SCRN(v, sl) { float kf = __uint_as_float((__float_as_uint(v) & 0xFFFFFC00u) | code); \
                      t2[sl] = __builtin_amdgcn_fmed3f(kf, t1[sl], t2[sl]); \
                      t1[sl] = fmaxf(t1[sl], kf); }
#pragma unroll
    for (int i = 0; i < 4; ++i) {
      SCRN(acc0[i], i);
      SCRN(acc1[i], 4 + i);
    }
#undef SCRN
  }

  // ---- merge: kk[pt][class][2] (16 classes = c16), then top-4 of 32 ----
  __syncthreads();
  float* kk = (float*)lds;  // 128 pts x 32 floats = 16KB
#pragma unroll
  for (int m = 0; m < 2; ++m)
#pragma unroll
    for (int i = 0; i < 4; ++i) {
      int pt = w * 32 + m * 16 + g * 4 + i;
      kk[pt * 32 + c16 * 2] = t1[m * 4 + i];
      kk[pt * 32 + c16 * 2 + 1] = t2[m * 4 + i];
    }
  __syncthreads();

  if (t < 128) {
    float f1 = -__builtin_inff(), f2v = f1, f3 = f1, f4 = f1;
#pragma unroll
    for (int j = 0; j < 32; ++j) {
      float v = kk[t * 32 + ((j + t) & 31)];
      float b1 = fminf(f1, v);   f1 = fmaxf(f1, v);
      float b2 = fminf(f2v, b1); f2v = fmaxf(f2v, b1);
      float b3 = fminf(f3, b2);  f3 = fmaxf(f3, b2);
      f4 = fmaxf(f4, b3);
    }
    u64 pk = (u64)(__float_as_uint(f1) & 1023u)
           | ((u64)(__float_as_uint(f2v) & 1023u) << 16)
           | ((u64)(__float_as_uint(f3) & 1023u) << 32)
           | ((u64)(__float_as_uint(f4) & 1023u) << 48);
    cand4[(size_t)bid * 128u + (unsigned)t] = pk;
  }
}

// ---------------- K2: candidate-parallel exact np-f32 rescore -----------------
extern "C" __global__ __launch_bounds__(256) void vq_r13_k2(const float* __restrict__ x,
                                                            const float* __restrict__ cb,
                                                            const u64* __restrict__ cand4,
                                                            const float* __restrict__ enrm,
                                                            float* __restrict__ outf) {
#pragma clang fp contract(off)
  __shared__ double dts[4][64];
  __shared__ float s1s[64];
  const int t = threadIdx.x;
  const int pl = t & 63;   // point within block
  const int c = t >> 6;    // candidate index = wave
  const unsigned p = blockIdx.x * 64u + (unsigned)pl;

  const u64 pk = cand4[p];
  const int code = (int)((pk >> (16 * c)) & 1023u);

  const size_t xoff = ((size_t)(p >> 12)) * 1048576u + (size_t)(p & 4095u);
  const float* e = cb + (size_t)code * 256u;

  double da = 0.0, db = 0.0;
  float hs1[2];
#pragma unroll
  for (int half = 0; half < 2; ++half) {
    float r[8];
#pragma unroll 2
    for (int i = 0; i < 128; i += 8) {
      const int dbase = half * 128 + i;
      float q[8], xv[8];
      *(float4*)(q) = *(const float4*)(e + dbase);
      *(float4*)(q + 4) = *(const float4*)(e + dbase + 4);
#pragma unroll
      for (int j = 0; j < 8; ++j) xv[j] = x[xoff + (size_t)(dbase + j) * 4096u];
#pragma unroll
      for (int j = 0; j < 8; ++j) {
        r[j] = (i == 0) ? __fmul_rn(xv[j], xv[j])
                        : __fadd_rn(r[j], __fmul_rn(xv[j], xv[j]));
        if (j & 1) db = fma((double)xv[j], (double)q[j], db);
        else       da = fma((double)xv[j], (double)q[j], da);
      }
    }
    hs1[half] = COMB(r);
  }
  dts[c][pl] = da + db;
  if (c == 0) s1s[pl] = __fadd_rn(hs1[0], hs1[1]);
  __syncthreads();

  if (t < 64) {  // wave 0 selects, packed candidate order, original tie-break
    const float s1v = s1s[pl];
    float bestd = __builtin_inff();
    int besti = 0x7FFFFFFF;
#pragma unroll
    for (int cc = 0; cc < 4; ++cc) {
      const int ccode = (int)((pk >> (16 * cc)) & 1023u);
      float dd = __fsub_rn(__fadd_rn(s1v, enrm[ccode]),
                           __fmul_rn(2.0f, (float)dts[cc][pl]));
      if (dd < bestd || (dd == bestd && ccode < besti)) { bestd = dd; besti = ccode; }
    }
    outf[IDX_OFF + p] = (float)besti;  // exact integer in f32

    float sum = bestd;  // loss partial: sum_c (x-q)^2 == s1 + s2 - 2*dot
#pragma unroll
    for (int off = 32; off > 0; off >>= 1) sum += __shfl_down(sum, off);
    if (pl == 0) atomicAdd(outf + LOSS_OFF, sum);
  }
}

// ---------------- K4: finalize loss in place -----------------------------------
extern "C" __global__ void vq_r13_k4(float* __restrict__ outf) {
  if (threadIdx.x == 0 && blockIdx.x == 0)
    outf[LOSS_OFF] = 2.0f * (outf[LOSS_OFF] / 33554432.0f);
}

// ---------------- K3: z_q via LDS rows, 1KB/instr float4 writes ----------------
extern "C" __global__ __launch_bounds__(256) void vq_r13_k3(const float* __restrict__ cb,
                                                            float* __restrict__ outf) {
  __shared__ float rows[32 * 257];  // +1-pad
  const int t = threadIdx.x;
  const unsigned p0 = blockIdx.x * 32u;  // 4096 blocks x 32 points
  const unsigned b = p0 >> 12, hw0 = p0 & 4095u;
  const float* idxf = outf + IDX_OFF;
  for (int i = 0; i < 32; ++i) {
    int row = ((int)idxf[p0 + (unsigned)i]) & 1023;  // broadcast load
    rows[i * 257 + t] = cb[(size_t)row * 256u + (unsigned)t];
  }
  __syncthreads();
  const int q = t & 7, cgrp = t >> 3;  // hw quad 0..7, c-group 0..31
  float* obase = outf + (size_t)b * 1048576u + hw0 + (unsigned)(q * 4);
#pragma unroll
  for (int cc = 0; cc < 8; ++cc) {
    int c = cgrp * 8 + cc;
    float4 v;
    v.x = rows[(q * 4 + 0) * 257 + c];
    v.y = rows[(q * 4 + 1) * 257 + c];
    v.z = rows[(q * 4 + 2) * 257 + c];
    v.w = rows[(q * 4 + 3) * 257 + c];
    *(float4*)(obase + (size_t)c * 4096u) = v;
  }
}

// ---------------- host ---------------------------------------------------------
extern "C" void kernel_launch(void* const* d_in, const int* in_sizes, int n_in,
                              void* d_out, int out_size, void* d_ws, size_t ws_size,
                              hipStream_t stream) {
  const float* x = (const float*)d_in[0];   // [32,256,64,64] f32
  const float* cb = (const float*)d_in[1];  // [1024,256] f32
  float* outf = (float*)d_out;              // f32 outputs
  unsigned char* img = (unsigned char*)d_out + IMG_BYTE;
  u64* cand4 = (u64*)((unsigned char*)d_out + CAND_BYTE);
  float* enrm = (float*)((unsigned char*)d_out + ENRM_BYTE);
  (void)in_sizes; (void)n_in; (void)out_size; (void)d_ws; (void)ws_size;

  vq_r13_k0<<<512, 256, 0, stream>>>(cb, img, outf);
  vq_r13_k0b<<<4, 256, 0, stream>>>(cb, enrm);
  vq_r13_k1<<<1024, 256, 0, stream>>>(x, img, cand4);
  vq_r13_k2<<<2048, 256, 0, stream>>>(x, cb, cand4, enrm, outf);
  vq_r13_k4<<<1, 64, 0, stream>>>(outf);
  vq_r13_k3<<<4096, 256, 0, stream>>>(cb, outf);
}

// Round 15
// 195.780 us; speedup vs baseline: 1.1399x; 1.1399x over previous
//
#include <hip/hip_runtime.h>

// VectorQuantizer on MI355X (gfx950). Round 14: consolidation — K1 = r10-best
// (m=4, 512 blocks, direct B loads) + s_setprio around MFMA (T5). K0b merged
// into K0; K4 folded into K3. 4 launches total.
// d_out (f32): [z_q 33554432][idx 131072][loss 1]  (out_size 33685505)
// Scratch inside z_q's byte region (overwritten by K3 at the end):
//   bytes [67108864, 67633152)  bf16 codebook image in MFMA-fragment order
//   bytes [68157440, 69206016)  cand4: u64[131072] packed top-4 codes
//   bytes [69206016, 69210112)  enrm: f32[1024] exact np-pairwise codebook norms
// Loss slot outf[33685504] = accumulator (K0 zeroes, K2 adds, K3 rescales).

typedef __attribute__((ext_vector_type(8))) short short8;
typedef __attribute__((ext_vector_type(4))) float f32x4;
typedef unsigned long long u64;

#define IDX_OFF   33554432u
#define LOSS_OFF  33685504u
#define IMG_BYTE  67108864u
#define CAND_BYTE 68157440u
#define ENRM_BYTE 69206016u

__device__ __forceinline__ unsigned short f2bf(float f) {
  unsigned u = __float_as_uint(f);
  unsigned r = (u + 0x7FFFu + ((u >> 16) & 1u)) >> 16;  // RNE
  return (unsigned short)r;
}

// numpy pairwise combine of 8 accumulators
#define COMB(r) __fadd_rn(__fadd_rn(__fadd_rn(r[0], r[1]), __fadd_rn(r[2], r[3])), \
                          __fadd_rn(__fadd_rn(r[4], r[5]), __fadd_rn(r[6], r[7])))

// ---------------- K0: codebook image (fragment order) + enrm + zero loss ------
// img: 16B at (s*8+ks)*1024 + lane*16 holds code s*16+(lane&15),
// d = ks*32 + (lane>>4)*8 + 0..7  (s = step index 0..63).
extern "C" __global__ __launch_bounds__(256) void vq_r14_k0(const float* __restrict__ cb,
                                                            unsigned char* __restrict__ img,
                                                            float* __restrict__ enrm,
                                                            float* __restrict__ outf) {
#pragma clang fp contract(off)
  unsigned tid = blockIdx.x * 256u + threadIdx.x;  // 131072 = (code, dpair)
  unsigned code = tid >> 7, dp = tid & 127u;
  const float* p = cb + (size_t)code * 256u + dp * 2u;
  unsigned u = ((unsigned)f2bf(p[1]) << 16) | (unsigned)f2bf(p[0]);
  unsigned s = code >> 4, c16 = code & 15;
  unsigned ks = dp >> 4, g = (dp >> 2) & 3, j = dp & 3;
  unsigned byte = (s * 8u + ks) * 1024u + (g * 16u + c16) * 16u + j * 4u;
  *(unsigned*)(img + byte) = u;
  if (tid == 0) outf[LOSS_OFF] = 0.0f;

  if (tid < 1024u) {  // exact np-f32 pairwise codebook norms (was K0b)
    const float* e = cb + (size_t)tid * 256u;
    float h[2];
#pragma unroll
    for (int half = 0; half < 2; ++half) {
      float r[8];
#pragma unroll
      for (int jj = 0; jj < 8; ++jj) {
        float v = e[half * 128 + jj];
        r[jj] = __fmul_rn(v, v);
      }
      for (int i = 8; i < 128; i += 8) {
#pragma unroll
        for (int jj = 0; jj < 8; ++jj) {
          float v = e[half * 128 + i + jj];
          r[jj] = __fadd_rn(r[jj], __fmul_rn(v, v));
        }
      }
      h[half] = COMB(r);
    }
    enrm[tid] = __fadd_rn(h[0], h[1]);
  }
}

// ---------------- K1: r10-best m=4 A-in-regs MFMA GEMM + setprio (T5) ---------
// 256 thr (4 waves), block = 256 pts x 1024 codes, 512 blocks (2/CU).
// Wave owns 64 pts (a[4][8] = 128 regs). B frags direct global->reg (L2-hot).
extern "C" __global__ __launch_bounds__(256, 2) void vq_r14_k1(const float* __restrict__ x,
                                                               const unsigned char* __restrict__ img,
                                                               u64* __restrict__ cand4) {
  __shared__ __attribute__((aligned(16))) char lds[32768];
  const int t = threadIdx.x;
  const int bid = blockIdx.x;  // 512 blocks
  const int lane = t & 63;
  const int w = t >> 6;
  const int g = lane >> 4, c16 = lane & 15;

  const size_t xbase = (size_t)(bid >> 4) * 1048576u + (size_t)(bid & 15) * 256u;

  // ---- A: 4 quarters of 64 pts staged via 32KB LDS transpose, frags to regs --
  short8 a[4][8];
  for (int q = 0; q < 4; ++q) {
#pragma unroll 4
    for (int s = 0; s < 8; ++s) {
      int flat = s * 256 + t;   // [0, 2048): 16 pt-groups x 128 dpairs
      int pt4 = flat & 15;
      int dp = flat >> 4;
      const float* px = x + xbase + (size_t)(2 * dp) * 4096u + (unsigned)(q * 64 + pt4 * 4);
      float4 fa = *(const float4*)px;           // d = 2*dp,   4 pts
      float4 fb = *(const float4*)(px + 4096);  // d = 2*dp+1, 4 pts
      const float* fap = (const float*)&fa;
      const float* fbp = (const float*)&fb;
#pragma unroll
      for (int k = 0; k < 4; ++k) {
        unsigned u = ((unsigned)f2bf(fbp[k]) << 16) | (unsigned)f2bf(fap[k]);
        int r = pt4 * 4 + k;  // local row 0..63
        *(unsigned*)(lds + r * 512 + ((dp * 4) ^ ((r & 31) << 2))) = u;
      }
    }
    __syncthreads();
    if (w == q) {
#pragma unroll
      for (int m = 0; m < 4; ++m) {
        const int r = m * 16 + c16;       // local row
        const int rsw = (r & 31) << 2;
#pragma unroll
        for (int ks = 0; ks < 8; ++ks) {
          union { unsigned q4[4]; short8 s8; } uu;
#pragma unroll
          for (int jj = 0; jj < 4; ++jj)
            uu.q4[jj] = *(const unsigned*)(lds + r * 512 + (((ks * 16 + g * 4 + jj) * 4) ^ rsw));
          a[m][ks] = uu.s8;
        }
      }
    }
    __syncthreads();
  }

  // ---- main loop: 64 steps, B frags direct from global (L2-hot) ----
  float t1[16], t2[16];
#pragma unroll
  for (int s = 0; s < 16; ++s) { t1[s] = -__builtin_inff(); t2[s] = -__builtin_inff(); }

  const unsigned char* gW = img + (unsigned)(lane * 16);
  for (int s = 0; s < 64; ++s) {
    const unsigned char* gs = gW + (unsigned)(s * 8192);
    short8 bf[8];
#pragma unroll
    for (int ks = 0; ks < 8; ++ks)
      bf[ks] = *(const short8*)(gs + ks * 1024);  // contiguous 1KB/wave
    f32x4 acc0 = (f32x4){0.f, 0.f, 0.f, 0.f};
    f32x4 acc1 = (f32x4){0.f, 0.f, 0.f, 0.f};
    f32x4 acc2 = (f32x4){0.f, 0.f, 0.f, 0.f};
    f32x4 acc3 = (f32x4){0.f, 0.f, 0.f, 0.f};
    __builtin_amdgcn_s_setprio(1);  // T5: favor this wave while MFMA cluster runs
#pragma unroll
    for (int ks = 0; ks < 8; ++ks) {
      acc0 = __builtin_amdgcn_mfma_f32_16x16x32_bf16(a[0][ks], bf[ks], acc0, 0, 0, 0);
      acc1 = __builtin_amdgcn_mfma_f32_16x16x32_bf16(a[1][ks], bf[ks], acc1, 0, 0, 0);
      acc2 = __builtin_amdgcn_mfma_f32_16x16x32_bf16(a[2][ks], bf[ks], acc2, 0, 0, 0);
      acc3 = __builtin_amdgcn_mfma_f32_16x16x32_bf16(a[3][ks], bf[ks], acc3, 0, 0, 0);
    }
    __builtin_amdgcn_s_setprio(0);
    const unsigned code = (unsigned)(s * 16 + c16);
#define SCRN(v, sl) { float kf = __uint_as_float((__float_as_uint(v) & 0xFFFFFC00u) | code); \
                      t2[sl] = __builtin_amdgcn_fmed3f(kf, t1[sl], t2[sl]); \
                      t1[sl] = fmaxf(t1[sl], kf); }
#pragma unroll
    for (int i = 0; i < 4; ++i) {
      SCRN(acc0[i], i);
      SCRN(acc1[i], 4 + i);
      SCRN(acc2[i], 8 + i);
      SCRN(acc3[i], 12 + i);
    }
#undef SCRN
  }

  // ---- merge: kk[pt][class][2] (16 classes = c16), then top-4 of 32 ----
  __syncthreads();
  float* kk = (float*)lds;  // 256 pts x 32 floats = 32KB
#pragma unroll
  for (int m = 0; m < 4; ++m)
#pragma unroll
    for (int i = 0; i < 4; ++i) {
      int pt = w * 64 + m * 16 + g * 4 + i;
      kk[pt * 32 + c16 * 2] = t1[m * 4 + i];
      kk[pt * 32 + c16 * 2 + 1] = t2[m * 4 + i];
    }
  __syncthreads();

  {
    float f1 = -__builtin_inff(), f2v = f1, f3 = f1, f4 = f1;
#pragma unroll
    for (int j = 0; j < 32; ++j) {
      float v = kk[t * 32 + ((j + t) & 31)];
      float b1 = fminf(f1, v);   f1 = fmaxf(f1, v);
      float b2 = fminf(f2v, b1); f2v = fmaxf(f2v, b1);
      float b3 = fminf(f3, b2);  f3 = fmaxf(f3, b2);
      f4 = fmaxf(f4, b3);
    }
    u64 pk = (u64)(__float_as_uint(f1) & 1023u)
           | ((u64)(__float_as_uint(f2v) & 1023u) << 16)
           | ((u64)(__float_as_uint(f3) & 1023u) << 32)
           | ((u64)(__float_as_uint(f4) & 1023u) << 48);
    cand4[(size_t)bid * 256u + (unsigned)t] = pk;
  }
}

// ---------------- K2: candidate-parallel exact np-f32 rescore -----------------
extern "C" __global__ __launch_bounds__(256) void vq_r14_k2(const float* __restrict__ x,
                                                            const float* __restrict__ cb,
                                                            const u64* __restrict__ cand4,
                                                            const float* __restrict__ enrm,
                                                            float* __restrict__ outf) {
#pragma clang fp contract(off)
  __shared__ double dts[4][64];
  __shared__ float s1s[64];
  const int t = threadIdx.x;
  const int pl = t & 63;   // point within block
  const int c = t >> 6;    // candidate index = wave
  const unsigned p = blockIdx.x * 64u + (unsigned)pl;

  const u64 pk = cand4[p];
  const int code = (int)((pk >> (16 * c)) & 1023u);

  const size_t xoff = ((size_t)(p >> 12)) * 1048576u + (size_t)(p & 4095u);
  const float* e = cb + (size_t)code * 256u;

  double da = 0.0, db = 0.0;
  float hs1[2];
#pragma unroll
  for (int half = 0; half < 2; ++half) {
    float r[8];
#pragma unroll 2
    for (int i = 0; i < 128; i += 8) {
      const int dbase = half * 128 + i;
      float q[8], xv[8];
      *(float4*)(q) = *(const float4*)(e + dbase);
      *(float4*)(q + 4) = *(const float4*)(e + dbase + 4);
#pragma unroll
      for (int j = 0; j < 8; ++j) xv[j] = x[xoff + (size_t)(dbase + j) * 4096u];
#pragma unroll
      for (int j = 0; j < 8; ++j) {
        r[j] = (i == 0) ? __fmul_rn(xv[j], xv[j])
                        : __fadd_rn(r[j], __fmul_rn(xv[j], xv[j]));
        if (j & 1) db = fma((double)xv[j], (double)q[j], db);
        else       da = fma((double)xv[j], (double)q[j], da);
      }
    }
    hs1[half] = COMB(r);
  }
  dts[c][pl] = da + db;
  if (c == 0) s1s[pl] = __fadd_rn(hs1[0], hs1[1]);
  __syncthreads();

  if (t < 64) {  // wave 0 selects, packed candidate order, original tie-break
    const float s1v = s1s[pl];
    float bestd = __builtin_inff();
    int besti = 0x7FFFFFFF;
#pragma unroll
    for (int cc = 0; cc < 4; ++cc) {
      const int ccode = (int)((pk >> (16 * cc)) & 1023u);
      float dd = __fsub_rn(__fadd_rn(s1v, enrm[ccode]),
                           __fmul_rn(2.0f, (float)dts[cc][pl]));
      if (dd < bestd || (dd == bestd && ccode < besti)) { bestd = dd; besti = ccode; }
    }
    outf[IDX_OFF + p] = (float)besti;  // exact integer in f32

    float sum = bestd;  // loss partial: sum_c (x-q)^2 == s1 + s2 - 2*dot
#pragma unroll
    for (int off = 32; off > 0; off >>= 1) sum += __shfl_down(sum, off);
    if (pl == 0) atomicAdd(outf + LOSS_OFF, sum);
  }
}

// ---------------- K3: z_q via LDS rows (1KB/instr) + loss finalize ------------
extern "C" __global__ __launch_bounds__(256) void vq_r14_k3(const float* __restrict__ cb,
                                                            float* __restrict__ outf) {
  __shared__ float rows[32 * 257];  // +1-pad
  const int t = threadIdx.x;
  if (blockIdx.x == 0 && t == 0)  // was K4: finalize loss in place
    outf[LOSS_OFF] = 2.0f * (outf[LOSS_OFF] / 33554432.0f);
  const unsigned p0 = blockIdx.x * 32u;  // 4096 blocks x 32 points
  const unsigned b = p0 >> 12, hw0 = p0 & 4095u;
  const float* idxf = outf + IDX_OFF;
  for (int i = 0; i < 32; ++i) {
    int row = ((int)idxf[p0 + (unsigned)i]) & 1023;  // broadcast load
    rows[i * 257 + t] = cb[(size_t)row * 256u + (unsigned)t];
  }
  __syncthreads();
  const int q = t & 7, cgrp = t >> 3;  // hw quad 0..7, c-group 0..31
  float* obase = outf + (size_t)b * 1048576u + hw0 + (unsigned)(q * 4);
#pragma unroll
  for (int cc = 0; cc < 8; ++cc) {
    int c = cgrp * 8 + cc;
    float4 v;
    v.x = rows[(q * 4 + 0) * 257 + c];
    v.y = rows[(q * 4 + 1) * 257 + c];
    v.z = rows[(q * 4 + 2) * 257 + c];
    v.w = rows[(q * 4 + 3) * 257 + c];
    *(float4*)(obase + (size_t)c * 4096u) = v;
  }
}

// ---------------- host ---------------------------------------------------------
extern "C" void kernel_launch(void* const* d_in, const int* in_sizes, int n_in,
                              void* d_out, int out_size, void* d_ws, size_t ws_size,
                              hipStream_t stream) {
  const float* x = (const float*)d_in[0];   // [32,256,64,64] f32
  const float* cb = (const float*)d_in[1];  // [1024,256] f32
  float* outf = (float*)d_out;              // f32 outputs
  unsigned char* img = (unsigned char*)d_out + IMG_BYTE;
  u64* cand4 = (u64*)((unsigned char*)d_out + CAND_BYTE);
  float* enrm = (float*)((unsigned char*)d_out + ENRM_BYTE);
  (void)in_sizes; (void)n_in; (void)out_size; (void)d_ws; (void)ws_size;

  vq_r14_k0<<<512, 256, 0, stream>>>(cb, img, enrm, outf);
  vq_r14_k1<<<512, 256, 0, stream>>>(x, img, cand4);
  vq_r14_k2<<<2048, 256, 0, stream>>>(x, cb, cand4, enrm, outf);
  vq_r14_k3<<<4096, 256, 0, stream>>>(cb, outf);
}